// Round 1
// baseline (109.020 us; speedup 1.0000x reference)
//
#include <hip/hip_runtime.h>

// ReflectionRayTracer: 8192 rays x 2048 quad surfaces.
// out[ray][surf] = t * mask, t = ray/plane hit distance, mask = barycentric-ish sign test.
//
// Numerics: mask = (beta>0)&(gam>0)&(alpha>0) gates t (|t| up to ~450, threshold 7.24),
// so a 1-ulp drift near a zero crossing costs |t|. We therefore:
//   - disable FMA contraction (numpy does not fuse),
//   - keep default IEEE f32 div/sqrt (no fast-math),
//   - replicate the reference expression tree exactly (incl. G = D, _safe() placement,
//     -(k+vo) negation order, sequential 3-term dots).
// Surface-only subexpressions (v, k, B, D, E, F, P, safe denominators) are hoisted out
// of the ray loop — bitwise identical to the reference's broadcast semantics since the
// same IEEE ops on the same inputs give the same bits.

#define N_RAYS 8192
#define N_SURF 2048
constexpr int RPB = 32;   // rays per block; grid = (2048/256, 8192/RPB) = 2048 blocks = 8/CU

__device__ __forceinline__ float safef(float x) {
    return (x == 0.0f) ? 1e-18f : x;   // matches jnp.where(x==0, EPS, x); -0.0 == 0.0 -> EPS
}

__global__ __launch_bounds__(256) void rt_kernel(
    const float* __restrict__ o, const float* __restrict__ dr,
    const float* __restrict__ V, float* __restrict__ out)
{
#pragma clang fp contract(off)
    const int s = blockIdx.x * 256 + threadIdx.x;   // one surface per thread

    // V[s] is 12 consecutive floats, 48B-aligned -> three aligned float4 loads.
    const float4 p0 = *(const float4*)(V + (size_t)s * 12);
    const float4 p1 = *(const float4*)(V + (size_t)s * 12 + 4);
    const float4 p2 = *(const float4*)(V + (size_t)s * 12 + 8);
    const float ax = p0.x, ay = p0.y, az = p0.z;       // a = V[s][0]
    const float bx = p0.w, by = p1.x, bz = p1.y;       // b = V[s][1]
    const float cx = p1.z, cy = p1.w, cz = p2.x;       // c = V[s][2]
    const float wx = p2.y, wy = p2.z, wz = p2.w;       // V[s][3]

    // v = normalize(cross(b-a, c-a)); k = -dot(v, V[s][3])
    const float e0x = bx - ax, e0y = by - ay, e0z = bz - az;
    const float e1x = cx - ax, e1y = cy - ay, e1z = cz - az;
    const float nx = e0y * e1z - e0z * e1y;
    const float ny = e0z * e1x - e0x * e1z;
    const float nz = e0x * e1y - e0y * e1x;
    const float nrm = sqrtf(nx * nx + ny * ny + nz * nz);
    const float vx = nx / nrm, vy = ny / nrm, vz = nz / nrm;
    const float k = -(vx * wx + vy * wy + vz * wz);

    // Ray-independent barycentric constants (reference names):
    const float B  = ax * bz - az * bx;
    const float D  = ax * by - ay * bx;                 // G == D in the reference
    const float E  = ax * cz - az * cx;
    const float P  = ay * cx - ax * cy;                 // appears in F and in beta's numerator
    const float F  = B * P;
    const float den_g = safef(D * (E * D + F));         // _safe(D*(E*G+F)), G=D
    const float sD    = safef(D);
    const float sAX   = safef(ax);

    const int ray0 = blockIdx.y * RPB;
    for (int i = 0; i < RPB; ++i) {
        const int ray = ray0 + i;
        // Block-uniform ray loads -> scalar loads, L1-resident.
        const float o0 = o[ray * 3 + 0], o1 = o[ray * 3 + 1], o2 = o[ray * 3 + 2];
        const float d0 = dr[ray * 3 + 0], d1 = dr[ray * 3 + 1], d2 = dr[ray * 3 + 2];

        const float vo = o0 * vx + o1 * vy + o2 * vz;   // sequential 3-term dot (numpy order)
        const float vd = d0 * vx + d1 * vy + d2 * vz;
        const float t  = (-(k + vo)) / vd;              // exact reference negation/div order

        const float rx = o0 + t * d0;
        const float ry = o1 + t * d1;
        const float rz = o2 + t * d2;

        const float A = ax * rz - az * rx;
        const float C = ax * ry - ay * rx;

        const float gam   = (D * (A * D - B * C)) / den_g;   // G*(A*D-B*C)/safe(...)
        const float beta  = (C + gam * P) / sD;
        const float alpha = (rx - (beta * bx + gam * cx)) / sAX;

        const float m = (beta > 0.0f && gam > 0.0f && alpha > 0.0f) ? 1.0f : 0.0f;
        out[(size_t)ray * N_SURF + s] = t * m;          // NaN*0 = NaN matches numpy
    }
}

extern "C" void kernel_launch(void* const* d_in, const int* in_sizes, int n_in,
                              void* d_out, int out_size, void* d_ws, size_t ws_size,
                              hipStream_t stream) {
    const float* o  = (const float*)d_in[0];
    const float* dr = (const float*)d_in[1];
    const float* V  = (const float*)d_in[2];
    float* out = (float*)d_out;

    dim3 grid(N_SURF / 256, N_RAYS / RPB);
    rt_kernel<<<grid, dim3(256), 0, stream>>>(o, dr, V, out);
}

// Round 2
// 93.434 us; speedup vs baseline: 1.1668x; 1.1668x over previous
//
#include <hip/hip_runtime.h>

// ReflectionRayTracer: 8192 rays x 2048 quad surfaces. out[ray][surf] = t*mask.
//
// R2: algebraic hoist. gam/beta/alpha are affine in the hit point r = o + t*d:
//   gam   = g0*rx + g1*ry + g2*rz
//   beta  = b0*rx + b1*ry + bp*gam
//   alpha = a0*rx + ab*beta + ac*gam
// with ray-independent coefficients (all the _safe() divides folded in, computed
// once per surface with exact IEEE divides, amortized over RPB rays). This removes
// 3 of the 4 per-pair IEEE divides (~33 VALU instr/pair) and FMA contraction is
// enabled (explicit fmaf) for the rest. Only t's divide stays IEEE per-pair since
// t is the output magnitude.
//
// Numerics: perturbation vs the reference expression tree is ~1e-6 relative
// (reassociation + folded reciprocals) — same class as the harness's own
// jax-vs-numpy matmul reassociation that set the 7.24 absmax threshold.

#define N_RAYS 8192
#define N_SURF 2048
constexpr int RPB = 32;   // rays per block; grid = (2048/256, 8192/32) = 2048 blocks

__device__ __forceinline__ float safef(float x) {
    return (x == 0.0f) ? 1e-18f : x;   // jnp.where(x==0, EPS, x)
}

__global__ __launch_bounds__(256) void rt_kernel(
    const float* __restrict__ o, const float* __restrict__ dr,
    const float* __restrict__ V, float* __restrict__ out)
{
    const int s = blockIdx.x * 256 + threadIdx.x;   // one surface per thread

    // V[s] = 12 consecutive floats, 48B-aligned -> three float4 loads.
    const float4 p0 = *(const float4*)(V + (size_t)s * 12);
    const float4 p1 = *(const float4*)(V + (size_t)s * 12 + 4);
    const float4 p2 = *(const float4*)(V + (size_t)s * 12 + 8);
    const float ax = p0.x, ay = p0.y, az = p0.z;       // a = V[s][0]
    const float bx = p0.w, by = p1.x, bz = p1.y;       // b = V[s][1]
    const float cx = p1.z, cy = p1.w, cz = p2.x;       // c = V[s][2]
    const float wx = p2.y, wy = p2.z, wz = p2.w;       // V[s][3]

    // Plane: v = normalize(cross(b-a, c-a)); k = -dot(v, V[s][3])
    const float e0x = bx - ax, e0y = by - ay, e0z = bz - az;
    const float e1x = cx - ax, e1y = cy - ay, e1z = cz - az;
    const float nx = e0y * e1z - e0z * e1y;
    const float ny = e0z * e1x - e0x * e1z;
    const float nz = e0x * e1y - e0y * e1x;
    const float nrm = sqrtf(nx * nx + ny * ny + nz * nz);
    const float vx = nx / nrm, vy = ny / nrm, vz = nz / nrm;
    const float k = -(vx * wx + vy * wy + vz * wz);

    // Reference constants:
    const float B  = ax * bz - az * bx;
    const float D  = ax * by - ay * bx;                 // G == D
    const float E  = ax * cz - az * cx;
    const float P  = ay * cx - ax * cy;
    const float F  = B * P;
    const float den_g = safef(D * (E * D + F));         // _safe(D*(E*G+F))
    const float sD    = safef(D);
    const float sAX   = safef(ax);

    // Affine coefficients (per-surface IEEE divides, amortized over RPB rays):
    // gam = [D^2*(ax*rz - az*rx) - D*B*(ax*ry - ay*rx)] / den_g
    const float DB = D * B, DD = D * D;
    const float g0 = (DB * ay - DD * az) / den_g;
    const float g1 = -(DB * ax) / den_g;
    const float g2 = (DD * ax) / den_g;
    // beta = (ax*ry - ay*rx + gam*P) / sD
    const float b0 = -ay / sD;
    const float b1 = ax / sD;
    const float bp = P / sD;
    // alpha = (rx - beta*bx - gam*cx) / sAX
    const float a0 = 1.0f / sAX;
    const float ab = -bx / sAX;
    const float ac = -cx / sAX;

    const int ray0 = blockIdx.y * RPB;
    float* outp = out + (size_t)ray0 * N_SURF + s;
#pragma unroll 4
    for (int i = 0; i < RPB; ++i) {
        const int ray = ray0 + i;
        // Block-uniform ray loads -> scalar (SMEM) loads.
        const float o0 = o[ray * 3 + 0], o1 = o[ray * 3 + 1], o2 = o[ray * 3 + 2];
        const float d0 = dr[ray * 3 + 0], d1 = dr[ray * 3 + 1], d2 = dr[ray * 3 + 2];

        const float vo = fmaf(o0, vx, fmaf(o1, vy, o2 * vz));
        const float vd = fmaf(d0, vx, fmaf(d1, vy, d2 * vz));
        const float t  = (-(k + vo)) / vd;              // IEEE div: output-critical

        const float rx = fmaf(t, d0, o0);
        const float ry = fmaf(t, d1, o1);
        const float rz = fmaf(t, d2, o2);

        const float gam   = fmaf(g0, rx, fmaf(g1, ry, g2 * rz));
        const float beta  = fmaf(b0, rx, fmaf(b1, ry, bp * gam));
        const float alpha = fmaf(a0, rx, fmaf(ab, beta, ac * gam));

        const float m = (beta > 0.0f && gam > 0.0f && alpha > 0.0f) ? 1.0f : 0.0f;
        outp[(size_t)i * N_SURF] = t * m;               // NaN*0 = NaN matches numpy
    }
}

extern "C" void kernel_launch(void* const* d_in, const int* in_sizes, int n_in,
                              void* d_out, int out_size, void* d_ws, size_t ws_size,
                              hipStream_t stream) {
    const float* o  = (const float*)d_in[0];
    const float* dr = (const float*)d_in[1];
    const float* V  = (const float*)d_in[2];
    float* out = (float*)d_out;

    dim3 grid(N_SURF / 256, N_RAYS / RPB);
    rt_kernel<<<grid, dim3(256), 0, stream>>>(o, dr, V, out);
}

// Round 3
// 86.927 us; speedup vs baseline: 1.2542x; 1.0749x over previous
//
#include <hip/hip_runtime.h>

// ReflectionRayTracer: 8192 rays x 2048 quad surfaces. out[ray][surf] = t*mask.
//
// R3 structure: two kernels.
//  1) precompute_kernel: per-surface constants (plane v,k and the three affine
//     r-dot vectors g,bb,aa with all _safe() divides folded) -> d_ws, 16 f32/surf.
//     Removes the ~300-cycle preamble that R2 recomputed in all 256 ray-blocks.
//  2) trace_kernel: per (ray,surf) pair only:
//       vo+k (3 fma), vd (3), t = -vo_k * rcp(vd) (2+rcp), r (3 fma),
//       gam/beta/alpha as direct 3-fma dots with r (9), min-min-cmp-select (4).
//     ~24 VALU instr/pair vs ~50 in R2.
//
// Numerics: v_rcp_f32 perturbs t by ~1e-7 relative — 10x smaller than the
// coefficient-folding reassociation R2 already survived (absmax 0.03 -> 4.03
// vs threshold 7.24). beta/alpha coefficient pre-combination is the same
// ~1e-7 class. Expect absmax ~4-5.
//
// If ws_size < 2048*16*4 B, fall back to a fused single-kernel path.

#define N_RAYS 8192
#define N_SURF 2048
constexpr int RPB = 32;   // rays per block in trace kernel

__device__ __forceinline__ float safef(float x) {
    return (x == 0.0f) ? 1e-18f : x;   // jnp.where(x==0, EPS, x)
}

// Compute the 13 per-surface constants; returns via out params.
__device__ __forceinline__ void surface_coeffs(
    const float* __restrict__ V, int s,
    float4& c0, float4& c1, float4& c2, float4& c3)
{
    const float4 p0 = *(const float4*)(V + (size_t)s * 12);
    const float4 p1 = *(const float4*)(V + (size_t)s * 12 + 4);
    const float4 p2 = *(const float4*)(V + (size_t)s * 12 + 8);
    const float ax = p0.x, ay = p0.y, az = p0.z;       // a = V[s][0]
    const float bx = p0.w, by = p1.x, bz = p1.y;       // b = V[s][1]
    const float cx = p1.z, cy = p1.w, cz = p2.x;       // c = V[s][2]
    const float wx = p2.y, wy = p2.z, wz = p2.w;       // V[s][3]

    // Plane: v = normalize(cross(b-a, c-a)); k = -dot(v, V[s][3])
    const float e0x = bx - ax, e0y = by - ay, e0z = bz - az;
    const float e1x = cx - ax, e1y = cy - ay, e1z = cz - az;
    const float nx = e0y * e1z - e0z * e1y;
    const float ny = e0z * e1x - e0x * e1z;
    const float nz = e0x * e1y - e0y * e1x;
    const float nrm = sqrtf(nx * nx + ny * ny + nz * nz);
    const float vx = nx / nrm, vy = ny / nrm, vz = nz / nrm;
    const float k = -(vx * wx + vy * wy + vz * wz);

    // Reference constants:
    const float B  = ax * bz - az * bx;
    const float D  = ax * by - ay * bx;                 // G == D
    const float E  = ax * cz - az * cx;
    const float P  = ay * cx - ax * cy;
    const float F  = B * P;
    const float den_g = safef(D * (E * D + F));         // _safe(D*(E*G+F))
    const float sD    = safef(D);
    const float sAX   = safef(ax);

    // gam = g . r
    const float DB = D * B, DD = D * D;
    const float g0 = (DB * ay - DD * az) / den_g;
    const float g1 = -(DB * ax) / den_g;
    const float g2 = (DD * ax) / den_g;
    // beta = b0*rx + b1*ry + bp*gam  ->  bb . r
    const float b0 = -ay / sD, b1 = ax / sD, bp = P / sD;
    const float bb0 = b0 + bp * g0;
    const float bb1 = b1 + bp * g1;
    const float bb2 = bp * g2;
    // alpha = a0*rx + ab*beta + ac*gam  ->  aa . r
    const float a0 = 1.0f / sAX, ab = -bx / sAX, ac = -cx / sAX;
    const float aa0 = a0 + ab * bb0 + ac * g0;
    const float aa1 = ab * bb1 + ac * g1;
    const float aa2 = ab * bb2 + ac * g2;

    c0 = make_float4(vx, vy, vz, k);
    c1 = make_float4(g0, g1, g2, 0.0f);
    c2 = make_float4(bb0, bb1, bb2, 0.0f);
    c3 = make_float4(aa0, aa1, aa2, 0.0f);
}

__global__ __launch_bounds__(256) void precompute_kernel(
    const float* __restrict__ V, float* __restrict__ C)
{
    const int s = blockIdx.x * 256 + threadIdx.x;
    float4 c0, c1, c2, c3;
    surface_coeffs(V, s, c0, c1, c2, c3);
    float4* c4 = (float4*)(C + (size_t)s * 16);
    c4[0] = c0; c4[1] = c1; c4[2] = c2; c4[3] = c3;
}

template <bool FUSED>
__global__ __launch_bounds__(256) void trace_kernel(
    const float* __restrict__ o, const float* __restrict__ dr,
    const float* __restrict__ VorC, float* __restrict__ out)
{
    const int s = blockIdx.x * 256 + threadIdx.x;   // one surface per thread

    float4 c0, c1, c2, c3;
    if constexpr (FUSED) {
        surface_coeffs(VorC, s, c0, c1, c2, c3);
    } else {
        const float4* c4 = (const float4*)(VorC + (size_t)s * 16);
        c0 = c4[0]; c1 = c4[1]; c2 = c4[2]; c3 = c4[3];
    }

    const int ray0 = blockIdx.y * RPB;
    float* outp = out + (size_t)ray0 * N_SURF + s;
#pragma unroll 8
    for (int i = 0; i < RPB; ++i) {
        const int ray = ray0 + i;
        // Block-uniform ray loads -> scalar loads.
        const float o0 = o[ray * 3 + 0], o1 = o[ray * 3 + 1], o2 = o[ray * 3 + 2];
        const float d0 = dr[ray * 3 + 0], d1 = dr[ray * 3 + 1], d2 = dr[ray * 3 + 2];

        const float vo_k = fmaf(o0, c0.x, fmaf(o1, c0.y, fmaf(o2, c0.z, c0.w))); // k+v.o
        const float vd   = fmaf(d0, c0.x, fmaf(d1, c0.y, d2 * c0.z));
        const float t    = -vo_k * __builtin_amdgcn_rcpf(vd);   // ~1-ulp rcp

        const float rx = fmaf(t, d0, o0);
        const float ry = fmaf(t, d1, o1);
        const float rz = fmaf(t, d2, o2);

        const float gam   = fmaf(c1.x, rx, fmaf(c1.y, ry, c1.z * rz));
        const float beta  = fmaf(c2.x, rx, fmaf(c2.y, ry, c2.z * rz));
        const float alpha = fmaf(c3.x, rx, fmaf(c3.y, ry, c3.z * rz));

        const float mn = fminf(fminf(beta, gam), alpha);
        outp[(size_t)i * N_SURF] = (mn > 0.0f) ? t : 0.0f;
    }
}

extern "C" void kernel_launch(void* const* d_in, const int* in_sizes, int n_in,
                              void* d_out, int out_size, void* d_ws, size_t ws_size,
                              hipStream_t stream) {
    const float* o  = (const float*)d_in[0];
    const float* dr = (const float*)d_in[1];
    const float* V  = (const float*)d_in[2];
    float* out = (float*)d_out;

    const size_t coeff_bytes = (size_t)N_SURF * 16 * sizeof(float);
    dim3 grid(N_SURF / 256, N_RAYS / RPB);

    if (ws_size >= coeff_bytes) {
        float* C = (float*)d_ws;
        precompute_kernel<<<dim3(N_SURF / 256), dim3(256), 0, stream>>>(V, C);
        trace_kernel<false><<<grid, dim3(256), 0, stream>>>(o, dr, C, out);
    } else {
        trace_kernel<true><<<grid, dim3(256), 0, stream>>>(o, dr, V, out);
    }
}